// Round 2
// baseline (245.622 us; speedup 1.0000x reference)
//
#include <hip/hip_runtime.h>
#include <hip/hip_bf16.h>

// B=1, Q=K=2048, C_IN=256, H=8, CH=32.
// Memory-bound on pair_bias (134 MB, read exactly once). Pipeline:
//   K0: weight transpose+bf16   K1: Q/K/V/gate projections (MFMA)
//   K2: flash attention w/ bias, fully transposed (S^T = K Q^T, O^T = V^T P)
//       so pair_bias is consumed as per-lane float4 loads.   K3: out-proj.
#define QN 2048
#define KN 2048
#define CIN 256
#define NH 8
#define CH 32
#define HC 256  // NH*CH

typedef __attribute__((ext_vector_type(8))) short short8;
typedef __attribute__((ext_vector_type(4))) float f32x4;
typedef __attribute__((ext_vector_type(4))) unsigned short u16x4;

__device__ __forceinline__ unsigned short f2bf(float f) {
  __hip_bfloat16 h = __float2bfloat16(f);
  return __builtin_bit_cast(unsigned short, h);
}

__device__ __forceinline__ short8 ld8(const unsigned short* p) {
  return *reinterpret_cast<const short8*>(p);
}
__device__ __forceinline__ f32x4 ld4f(const float* p) {
  return *reinterpret_cast<const f32x4*>(p);
}

// ---------------- K0: weight transpose + f32->bf16 ----------------
// wT[z][n][k] for z in {q,k,v,g,o}; src matrices are [k][n] row-major.
__global__ __launch_bounds__(256) void k0_wtrans(
    const float* __restrict__ wq, const float* __restrict__ wk,
    const float* __restrict__ wv, const float* __restrict__ wg,
    const float* __restrict__ wo, unsigned short* __restrict__ wT) {
  __shared__ float tile[32][33];
  const int z = blockIdx.z;
  const float* src = (z == 0) ? wq : (z == 1) ? wk : (z == 2) ? wv : (z == 3) ? wg : wo;
  unsigned short* dst = wT + (size_t)z * CIN * CIN;
  const int kb = blockIdx.x * 32, nb = blockIdx.y * 32;
  const int tc = threadIdx.x & 31, tr = threadIdx.x >> 5;
#pragma unroll
  for (int p = 0; p < 4; ++p) {
    int r = p * 8 + tr;
    tile[r][tc] = src[(size_t)(kb + r) * CIN + nb + tc];
  }
  __syncthreads();
#pragma unroll
  for (int p = 0; p < 4; ++p) {
    int n = p * 8 + tr;
    dst[(size_t)(nb + n) * CIN + kb + tc] = f2bf(tile[tc][n]);
  }
}

// ---------------- K1: projections ----------------
// z=0: qh[h][q][ch]  (scaled 1/sqrt(32))   z=1: kh[h][k][ch]
// z=2: vT[h][ch][k]                        z=3: gate[q][h*32+ch] = sigmoid(.+bg)
__global__ __launch_bounds__(256) void k1_proj(
    const float* __restrict__ qx, const float* __restrict__ kvx,
    const unsigned short* __restrict__ wT, const float* __restrict__ bg,
    unsigned short* __restrict__ qh, unsigned short* __restrict__ kh,
    unsigned short* __restrict__ vT, float* __restrict__ gate) {
  const int z = blockIdx.z;
  const float* __restrict__ X = (z == 0 || z == 3) ? qx : kvx;
  const unsigned short* __restrict__ W = wT + (size_t)z * CIN * CIN;
  const int tid = threadIdx.x;
  const int w = tid >> 6, l = tid & 63, l15 = l & 15, g = l >> 4;
  const int row0 = blockIdx.x * 64 + (w >> 1) * 32;
  const int col0 = blockIdx.y * 64 + (w & 1) * 32;
  f32x4 acc[2][2] = {};
  for (int kk = 0; kk < CIN; kk += 32) {
    short8 a[2], b[2];
#pragma unroll
    for (int fi = 0; fi < 2; ++fi) {
      const float* ap = X + (size_t)(row0 + fi * 16 + l15) * CIN + kk + g * 8;
      const float4 lo = *reinterpret_cast<const float4*>(ap);
      const float4 hi = *reinterpret_cast<const float4*>(ap + 4);
      short8 v;
      v[0] = (short)f2bf(lo.x); v[1] = (short)f2bf(lo.y);
      v[2] = (short)f2bf(lo.z); v[3] = (short)f2bf(lo.w);
      v[4] = (short)f2bf(hi.x); v[5] = (short)f2bf(hi.y);
      v[6] = (short)f2bf(hi.z); v[7] = (short)f2bf(hi.w);
      a[fi] = v;
    }
#pragma unroll
    for (int fj = 0; fj < 2; ++fj)
      b[fj] = ld8(W + (size_t)(col0 + fj * 16 + l15) * CIN + kk + g * 8);
#pragma unroll
    for (int fi = 0; fi < 2; ++fi)
#pragma unroll
      for (int fj = 0; fj < 2; ++fj)
        acc[fi][fj] = __builtin_amdgcn_mfma_f32_16x16x32_bf16(a[fi], b[fj], acc[fi][fj], 0, 0, 0);
  }
#pragma unroll
  for (int fi = 0; fi < 2; ++fi)
#pragma unroll
    for (int fj = 0; fj < 2; ++fj)
#pragma unroll
      for (int r = 0; r < 4; ++r) {
        const int row = row0 + fi * 16 + g * 4 + r;
        const int col = col0 + fj * 16 + l15;
        const float v = acc[fi][fj][r];
        if (z == 0) {
          qh[((size_t)(col >> 5) * QN + row) * CH + (col & 31)] = f2bf(v * 0.17677669529663687f);
        } else if (z == 1) {
          kh[((size_t)(col >> 5) * KN + row) * CH + (col & 31)] = f2bf(v);
        } else if (z == 2) {
          vT[((size_t)(col >> 5) * CH + (col & 31)) * KN + row] = f2bf(v);
        } else {
          gate[(size_t)row * HC + col] = 1.f / (1.f + __expf(-(v + bg[col])));
        }
      }
}

// ---------------- K2: flash attention with pair bias (transposed) ----------------
// Block = (q-strip of 16 rows, head), 4 waves, wave w owns k-chunk [w*512,(w+1)*512).
// Per 64-k tile:
//   S^T = mfma(A=K rows, B=Q rows, C = pair_bias^T + mask_bias): D col = q, row = k
//   -> bias enters as per-lane float4 (contiguous in k), prefetched 1 tile.
//   softmax per-lane over 16 k-values + 2 shfl_xor (lanes sharing q: ^16, ^32);
//   m/l/rescale per-lane scalars (q = lane&15 = output column of O^T).
//   P packed as ushort4 -> 4x ds_write_b64 -> 2x ds_read_b128 (B-frag), no barrier.
//   O^T = mfma(A=vT rows, B=P): col = q matches softmax state.
__global__ __launch_bounds__(256, 4) void k2_attn(
    const unsigned short* __restrict__ qh, const unsigned short* __restrict__ kh,
    const unsigned short* __restrict__ vT, const float* __restrict__ pb_all,
    const float* __restrict__ mb, const float* __restrict__ gate,
    unsigned short* __restrict__ og) {
  __shared__ __align__(16) unsigned short p_lds[4][16][72];  // pitch 72: conflict-free b64/b128
  __shared__ float o_lds[4][16][33];
  __shared__ float ml_lds[4][2][16];
  const int h = blockIdx.y;
  const int qb = blockIdx.x * 16;
  const int tid = threadIdx.x;
  const int w = tid >> 6, l = tid & 63, l15 = l & 15, g = l >> 4;
  const unsigned short* __restrict__ qp = qh + ((size_t)h * QN + qb) * CH;
  const unsigned short* __restrict__ kp = kh + (size_t)h * KN * CH;
  const unsigned short* __restrict__ vp0 = vT + ((size_t)h * CH + l15) * KN;
  const unsigned short* __restrict__ vp1 = vp0 + 16 * KN;
  const int k0 = w * (KN / 4);
  // per-lane bias row pointer: row q = qb+l15, col base k0 + g*4
  const float* __restrict__ pbl = pb_all + ((size_t)h * QN + qb + l15) * KN + k0 + g * 4;
  const float* __restrict__ mbl = mb + k0 + g * 4;

  // Q B-fragment: lane l15 = q, elements d = g*8..+7
  const short8 b_q = ld8(qp + l15 * CH + g * 8);
  f32x4 o0 = {}, o1 = {};
  float m = -3e38f, lsum = 0.f;
  f32x4 bc[4], bn[4];
#pragma unroll
  for (int kb = 0; kb < 4; ++kb) bc[kb] = ld4f(pbl + kb * 16);

  for (int t = 0; t < 8; ++t) {
    const int kt = k0 + t * 64;
    // prefetch next tile's pair bias (the HBM stream)
    if (t < 7) {
#pragma unroll
      for (int kb = 0; kb < 4; ++kb) bn[kb] = ld4f(pbl + (t + 1) * 64 + kb * 16);
    }
    // current-tile V (A-frags for O^T), issued early, consumed after softmax
    const short8 av00 = ld8(vp0 + kt + g * 8);
    const short8 av01 = ld8(vp0 + kt + 32 + g * 8);
    const short8 av10 = ld8(vp1 + kt + g * 8);
    const short8 av11 = ld8(vp1 + kt + 32 + g * 8);
    // mask bias (8 KB, cache-hot)
    f32x4 mb4[4];
#pragma unroll
    for (int kb = 0; kb < 4; ++kb) mb4[kb] = ld4f(mbl + t * 64 + kb * 16);
    // S^T: A = K rows (lane l15 = k_local), B = Q rows, C = bias
    f32x4 s[4];
#pragma unroll
    for (int kb = 0; kb < 4; ++kb) {
      const short8 ak = ld8(kp + (size_t)(kt + kb * 16 + l15) * CH + g * 8);
      f32x4 cb;
#pragma unroll
      for (int r = 0; r < 4; ++r) cb[r] = bc[kb][r] + mb4[kb][r];
      s[kb] = __builtin_amdgcn_mfma_f32_16x16x32_bf16(ak, b_q, cb, 0, 0, 0);
    }
    // online softmax for row q = l15 (per-lane over 16 values, then lanes ^16 ^32)
    float smax = fmaxf(fmaxf(s[0][0], s[0][1]), fmaxf(s[0][2], s[0][3]));
#pragma unroll
    for (int kb = 1; kb < 4; ++kb) {
      smax = fmaxf(smax, fmaxf(fmaxf(s[kb][0], s[kb][1]), fmaxf(s[kb][2], s[kb][3])));
    }
    smax = fmaxf(smax, __shfl_xor(smax, 16));
    smax = fmaxf(smax, __shfl_xor(smax, 32));
    const float mn = fmaxf(m, smax);
    const float sc = __expf(m - mn);
    m = mn;
    float ps = 0.f;
#pragma unroll
    for (int kb = 0; kb < 4; ++kb)
#pragma unroll
      for (int r = 0; r < 4; ++r) {
        const float p = __expf(s[kb][r] - m);
        s[kb][r] = p;
        ps += p;
      }
    ps += __shfl_xor(ps, 16);
    ps += __shfl_xor(ps, 32);
    lsum = lsum * sc + ps;
#pragma unroll
    for (int r = 0; r < 4; ++r) { o0[r] *= sc; o1[r] *= sc; }
    // P -> LDS: lane holds P[q=l15][k = kb*16+g*4+r], contiguous in r -> b64 writes
#pragma unroll
    for (int kb = 0; kb < 4; ++kb) {
      u16x4 pk;
#pragma unroll
      for (int r = 0; r < 4; ++r) pk[r] = f2bf(s[kb][r]);
      *reinterpret_cast<u16x4*>(&p_lds[w][l15][kb * 16 + g * 4]) = pk;
    }
    // B-frags: P[q=l15][k-slice], 16B reads (same wave, no barrier)
    const short8 bp0 = ld8(&p_lds[w][l15][g * 8]);
    const short8 bp1 = ld8(&p_lds[w][l15][32 + g * 8]);
    // O^T += V^T P  (D col = q = l15, row = d_local = g*4+r)
    o0 = __builtin_amdgcn_mfma_f32_16x16x32_bf16(av00, bp0, o0, 0, 0, 0);
    o0 = __builtin_amdgcn_mfma_f32_16x16x32_bf16(av01, bp1, o0, 0, 0, 0);
    o1 = __builtin_amdgcn_mfma_f32_16x16x32_bf16(av10, bp0, o1, 0, 0, 0);
    o1 = __builtin_amdgcn_mfma_f32_16x16x32_bf16(av11, bp1, o1, 0, 0, 0);
#pragma unroll
    for (int kb = 0; kb < 4; ++kb) bc[kb] = bn[kb];
  }
  // publish per-chunk partials: o_lds[w][q][d]
#pragma unroll
  for (int r = 0; r < 4; ++r) {
    o_lds[w][l15][g * 4 + r] = o0[r];
    o_lds[w][l15][16 + g * 4 + r] = o1[r];
  }
  if (l < 16) {
    ml_lds[w][0][l15] = m;
    ml_lds[w][1][l15] = lsum;
  }
  __syncthreads();
  // combine 4 chunks, apply gate, emit bf16 [q][h*32+ch]
#pragma unroll
  for (int it = 0; it < 2; ++it) {
    const int e = tid + it * 256;
    const int ql = e >> 5, ch = e & 31;
    const float m01 = fmaxf(ml_lds[0][0][ql], ml_lds[1][0][ql]);
    const float m23 = fmaxf(ml_lds[2][0][ql], ml_lds[3][0][ql]);
    const float mm = fmaxf(m01, m23);
    float L = 0.f, acc = 0.f;
#pragma unroll
    for (int c = 0; c < 4; ++c) {
      const float sc = __expf(ml_lds[c][0][ql] - mm);
      L += ml_lds[c][1][ql] * sc;
      acc += o_lds[c][ql][ch] * sc;
    }
    const size_t idx = (size_t)(qb + ql) * HC + h * CH + ch;
    og[idx] = f2bf((acc / L) * gate[idx]);
  }
}

// ---------------- K3: output projection + bias ----------------
__global__ __launch_bounds__(256) void k3_oproj(
    const unsigned short* __restrict__ og, const unsigned short* __restrict__ wToT,
    const float* __restrict__ bo, float* __restrict__ out) {
  const int tid = threadIdx.x;
  const int w = tid >> 6, l = tid & 63, l15 = l & 15, g = l >> 4;
  const int row0 = blockIdx.x * 64 + (w >> 1) * 32;
  const int col0 = blockIdx.y * 64 + (w & 1) * 32;
  f32x4 acc[2][2] = {};
  for (int kk = 0; kk < HC; kk += 32) {
    short8 a[2], b[2];
#pragma unroll
    for (int fi = 0; fi < 2; ++fi)
      a[fi] = ld8(og + (size_t)(row0 + fi * 16 + l15) * HC + kk + g * 8);
#pragma unroll
    for (int fj = 0; fj < 2; ++fj)
      b[fj] = ld8(wToT + (size_t)(col0 + fj * 16 + l15) * HC + kk + g * 8);
#pragma unroll
    for (int fi = 0; fi < 2; ++fi)
#pragma unroll
      for (int fj = 0; fj < 2; ++fj)
        acc[fi][fj] = __builtin_amdgcn_mfma_f32_16x16x32_bf16(a[fi], b[fj], acc[fi][fj], 0, 0, 0);
  }
#pragma unroll
  for (int fi = 0; fi < 2; ++fi)
#pragma unroll
    for (int fj = 0; fj < 2; ++fj)
#pragma unroll
      for (int r = 0; r < 4; ++r) {
        const int row = row0 + fi * 16 + g * 4 + r;
        const int col = col0 + fj * 16 + l15;
        out[(size_t)row * CIN + col] = acc[fi][fj][r] + bo[col];
      }
}

extern "C" void kernel_launch(void* const* d_in, const int* in_sizes, int n_in,
                              void* d_out, int out_size, void* d_ws, size_t ws_size,
                              hipStream_t stream) {
  const float* qx = (const float*)d_in[0];
  const float* kvx = (const float*)d_in[1];
  const float* pb = (const float*)d_in[2];
  const float* mbias = (const float*)d_in[3];
  const float* wq = (const float*)d_in[4];
  const float* wk = (const float*)d_in[5];
  const float* wv = (const float*)d_in[6];
  const float* wg = (const float*)d_in[7];
  const float* bg = (const float*)d_in[8];
  const float* wo = (const float*)d_in[9];
  const float* bo = (const float*)d_in[10];
  char* ws = (char*)d_ws;
  // workspace layout (bytes): wT 655360 | qh 1M | kh 1M | vT 1M | og 1M | gate 2M
  unsigned short* wT = (unsigned short*)(ws);
  unsigned short* qh = (unsigned short*)(ws + 655360);
  unsigned short* kh = (unsigned short*)(ws + 655360 + (1u << 20));
  unsigned short* vT = (unsigned short*)(ws + 655360 + 2u * (1u << 20));
  unsigned short* og = (unsigned short*)(ws + 655360 + 3u * (1u << 20));
  float* gate = (float*)(ws + 655360 + 4u * (1u << 20));
  float* out = (float*)d_out;

  k0_wtrans<<<dim3(8, 8, 5), 256, 0, stream>>>(wq, wk, wv, wg, wo, wT);
  k1_proj<<<dim3(32, 4, 4), 256, 0, stream>>>(qx, kvx, wT, bg, qh, kh, vT, gate);
  k2_attn<<<dim3(128, 8), 256, 0, stream>>>(qh, kh, vT, pb, mbias, gate, og);
  k3_oproj<<<dim3(32, 4), 256, 0, stream>>>(og, wT + 4 * 256 * 256, bo, out);
}

// Round 4
// 245.518 us; speedup vs baseline: 1.0004x; 1.0004x over previous
//
#include <hip/hip_runtime.h>
#include <hip/hip_bf16.h>

// B=1, Q=K=2048, C_IN=256, H=8, CH=32.
// Memory-bound on pair_bias (134 MB, read exactly once). Pipeline:
//   K0: weight transpose+bf16   K1: Q/K/V/gate projections (MFMA);
//       K and V are emitted in MFMA-fragment-contiguous layouts so K2's
//       K/V loads are single 1KB coalesced wave loads.
//   K2: flash attention w/ bias, transposed (S^T = K Q^T, O^T = V^T P).
//       Load order per tile: V, mb, K first; NEXT-tile bias prefetch LAST
//       (so the first MFMA's vmcnt wait never drains the bias stream).
//   K3: gated out-proj GEMM.
#define QN 2048
#define KN 2048
#define CIN 256
#define NH 8
#define CH 32
#define HC 256  // NH*CH

typedef __attribute__((ext_vector_type(8))) short short8;
typedef __attribute__((ext_vector_type(4))) float f32x4;
typedef __attribute__((ext_vector_type(4))) unsigned short u16x4;

__device__ __forceinline__ unsigned short f2bf(float f) {
  __hip_bfloat16 h = __float2bfloat16(f);
  return __builtin_bit_cast(unsigned short, h);
}

__device__ __forceinline__ short8 ld8(const unsigned short* p) {
  return *reinterpret_cast<const short8*>(p);
}
__device__ __forceinline__ f32x4 ld4f(const float* p) {
  return *reinterpret_cast<const f32x4*>(p);
}

// ---------------- K0: weight transpose + f32->bf16 ----------------
// wT[z][n][k] for z in {q,k,v,g,o}; src matrices are [k][n] row-major.
__global__ __launch_bounds__(256) void k0_wtrans(
    const float* __restrict__ wq, const float* __restrict__ wk,
    const float* __restrict__ wv, const float* __restrict__ wg,
    const float* __restrict__ wo, unsigned short* __restrict__ wT) {
  __shared__ float tile[32][33];
  const int z = blockIdx.z;
  const float* src = (z == 0) ? wq : (z == 1) ? wk : (z == 2) ? wv : (z == 3) ? wg : wo;
  unsigned short* dst = wT + (size_t)z * CIN * CIN;
  const int kb = blockIdx.x * 32, nb = blockIdx.y * 32;
  const int tc = threadIdx.x & 31, tr = threadIdx.x >> 5;
#pragma unroll
  for (int p = 0; p < 4; ++p) {
    int r = p * 8 + tr;
    tile[r][tc] = src[(size_t)(kb + r) * CIN + nb + tc];
  }
  __syncthreads();
#pragma unroll
  for (int p = 0; p < 4; ++p) {
    int n = p * 8 + tr;
    dst[(size_t)(nb + n) * CIN + kb + tc] = f2bf(tile[tc][n]);
  }
}

// ---------------- K1: projections ----------------
// z=0: qh[h][q][ch] (scaled 1/sqrt(32))
// z=1: kh2[h][k>>4][g=ch>>3][l15=k&15][e=ch&7]          (QK A-frag order)
// z=2: va [h][c=k>>5][u=ch>>4][g=(k&31)>>3][ch&15][k&7] (PV A-frag order)
// z=3: gate[q][h*32+ch] = sigmoid(.+bg)
__global__ __launch_bounds__(256) void k1_proj(
    const float* __restrict__ qx, const float* __restrict__ kvx,
    const unsigned short* __restrict__ wT, const float* __restrict__ bg,
    unsigned short* __restrict__ qh, unsigned short* __restrict__ kh2,
    unsigned short* __restrict__ va, float* __restrict__ gate) {
  const int z = blockIdx.z;
  const float* __restrict__ X = (z == 0 || z == 3) ? qx : kvx;
  const unsigned short* __restrict__ W = wT + (size_t)z * CIN * CIN;
  const int tid = threadIdx.x;
  const int w = tid >> 6, l = tid & 63, l15 = l & 15, g = l >> 4;
  const int row0 = blockIdx.x * 64 + (w >> 1) * 32;
  const int col0 = blockIdx.y * 64 + (w & 1) * 32;
  f32x4 acc[2][2] = {};
  for (int kk = 0; kk < CIN; kk += 32) {
    short8 a[2], b[2];
#pragma unroll
    for (int fi = 0; fi < 2; ++fi) {
      const float* ap = X + (size_t)(row0 + fi * 16 + l15) * CIN + kk + g * 8;
      const float4 lo = *reinterpret_cast<const float4*>(ap);
      const float4 hi = *reinterpret_cast<const float4*>(ap + 4);
      short8 v;
      v[0] = (short)f2bf(lo.x); v[1] = (short)f2bf(lo.y);
      v[2] = (short)f2bf(lo.z); v[3] = (short)f2bf(lo.w);
      v[4] = (short)f2bf(hi.x); v[5] = (short)f2bf(hi.y);
      v[6] = (short)f2bf(hi.z); v[7] = (short)f2bf(hi.w);
      a[fi] = v;
    }
#pragma unroll
    for (int fj = 0; fj < 2; ++fj)
      b[fj] = ld8(W + (size_t)(col0 + fj * 16 + l15) * CIN + kk + g * 8);
#pragma unroll
    for (int fi = 0; fi < 2; ++fi)
#pragma unroll
      for (int fj = 0; fj < 2; ++fj)
        acc[fi][fj] = __builtin_amdgcn_mfma_f32_16x16x32_bf16(a[fi], b[fj], acc[fi][fj], 0, 0, 0);
  }
#pragma unroll
  for (int fi = 0; fi < 2; ++fi)
#pragma unroll
    for (int fj = 0; fj < 2; ++fj)
#pragma unroll
      for (int r = 0; r < 4; ++r) {
        const int row = row0 + fi * 16 + g * 4 + r;
        const int col = col0 + fj * 16 + l15;
        const float v = acc[fi][fj][r];
        const int hh = col >> 5, ch = col & 31;
        if (z == 0) {
          qh[((size_t)hh * QN + row) * CH + ch] = f2bf(v * 0.17677669529663687f);
        } else if (z == 1) {
          kh2[(size_t)hh * 65536 +
              ((((row >> 4) * 4 + (ch >> 3)) * 16 + (row & 15)) * 8 + (ch & 7))] = f2bf(v);
        } else if (z == 2) {
          va[(size_t)hh * 65536 +
             (((((row >> 5) * 2 + (ch >> 4)) * 4 + ((row & 31) >> 3)) * 16 + (ch & 15)) * 8 +
              (row & 7))] = f2bf(v);
        } else {
          gate[(size_t)row * HC + col] = 1.f / (1.f + __expf(-(v + bg[col])));
        }
      }
}

// ---------------- K2: flash attention with pair bias (transposed) ----------------
// Block = (q-strip of 16 rows, head), 4 waves, wave w owns k-chunk [w*512,(w+1)*512).
// Per 64-k tile:
//   S^T = mfma(A=K frags, B=Q rows, C = pair_bias^T + mask_bias): D col=q, row=k.
//   Softmax per-lane over 16 k + 2 shfl_xor (^16,^32); m/l per-lane scalars.
//   P -> LDS b64 writes -> b128 B-frags (same wave, no barrier).
//   O^T = mfma(A=V frags, B=P).
// Load order: V frags, mb, K frags (current tile) FIRST; bias(t+1) LAST.
__global__ __launch_bounds__(256, 4) void k2_attn(
    const unsigned short* __restrict__ qh, const unsigned short* __restrict__ kh2,
    const unsigned short* __restrict__ va, const float* __restrict__ pb_all,
    const float* __restrict__ mb, const float* __restrict__ gate,
    unsigned short* __restrict__ og) {
  __shared__ __align__(16) unsigned short p_lds[4][16][72];
  __shared__ float o_lds[4][16][33];
  __shared__ float ml_lds[4][2][16];
  const int h = blockIdx.y;
  const int qb = blockIdx.x * 16;
  const int tid = threadIdx.x;
  const int w = tid >> 6, l = tid & 63, l15 = l & 15, g = l >> 4;
  const unsigned short* __restrict__ qp = qh + ((size_t)h * QN + qb) * CH;
  const unsigned short* __restrict__ khH = kh2 + (size_t)h * 65536;
  const unsigned short* __restrict__ vaH = va + (size_t)h * 65536;
  const int k0 = w * (KN / 4);
  const float* __restrict__ pbl = pb_all + ((size_t)h * QN + qb + l15) * KN + k0 + g * 4;
  const float* __restrict__ mbl = mb + k0 + g * 4;

  const short8 b_q = ld8(qp + l15 * CH + g * 8);
  f32x4 o0 = {}, o1 = {};
  float m = -3e38f, lsum = 0.f;
  f32x4 bc[4], bn[4];
#pragma unroll
  for (int kb = 0; kb < 4; ++kb) bc[kb] = ld4f(pbl + kb * 16);

  for (int t = 0; t < 8; ++t) {
    const int kt = k0 + t * 64;
    const int c = kt >> 5;  // 32-k chunk index (even)
    // ---- current-tile loads FIRST (fragment-contiguous: 1KB coalesced each)
    const short8 av00 = ld8(vaH + ((size_t)(c + 0) * 2 + 0) * 512 + l * 8);
    const short8 av01 = ld8(vaH + ((size_t)(c + 1) * 2 + 0) * 512 + l * 8);
    const short8 av10 = ld8(vaH + ((size_t)(c + 0) * 2 + 1) * 512 + l * 8);
    const short8 av11 = ld8(vaH + ((size_t)(c + 1) * 2 + 1) * 512 + l * 8);
    f32x4 mb4[4];
#pragma unroll
    for (int kb = 0; kb < 4; ++kb) mb4[kb] = ld4f(mbl + t * 64 + kb * 16);
    short8 ak[4];
#pragma unroll
    for (int kb = 0; kb < 4; ++kb)
      ak[kb] = ld8(khH + ((size_t)((kt >> 4) + kb) * 4 + g) * 128 + l15 * 8);
    // ---- next-tile bias prefetch LAST: stays in flight through softmax+PV
    if (t < 7) {
#pragma unroll
      for (int kb = 0; kb < 4; ++kb) bn[kb] = ld4f(pbl + (t + 1) * 64 + kb * 16);
    }
    // ---- S^T
    f32x4 s[4];
#pragma unroll
    for (int kb = 0; kb < 4; ++kb) {
      f32x4 cb;
#pragma unroll
      for (int r = 0; r < 4; ++r) cb[r] = bc[kb][r] + mb4[kb][r];
      s[kb] = __builtin_amdgcn_mfma_f32_16x16x32_bf16(ak[kb], b_q, cb, 0, 0, 0);
    }
    // ---- online softmax (row q = l15)
    float smax = fmaxf(fmaxf(s[0][0], s[0][1]), fmaxf(s[0][2], s[0][3]));
#pragma unroll
    for (int kb = 1; kb < 4; ++kb)
      smax = fmaxf(smax, fmaxf(fmaxf(s[kb][0], s[kb][1]), fmaxf(s[kb][2], s[kb][3])));
    smax = fmaxf(smax, __shfl_xor(smax, 16));
    smax = fmaxf(smax, __shfl_xor(smax, 32));
    const float mn = fmaxf(m, smax);
    const float sc = __expf(m - mn);
    m = mn;
    float ps = 0.f;
#pragma unroll
    for (int kb = 0; kb < 4; ++kb)
#pragma unroll
      for (int r = 0; r < 4; ++r) {
        const float p = __expf(s[kb][r] - m);
        s[kb][r] = p;
        ps += p;
      }
    ps += __shfl_xor(ps, 16);
    ps += __shfl_xor(ps, 32);
    lsum = lsum * sc + ps;
#pragma unroll
    for (int r = 0; r < 4; ++r) { o0[r] *= sc; o1[r] *= sc; }
    // ---- P -> LDS (b64 writes), read back as B-frags (b128), same wave
#pragma unroll
    for (int kb = 0; kb < 4; ++kb) {
      u16x4 pk;
#pragma unroll
      for (int r = 0; r < 4; ++r) pk[r] = f2bf(s[kb][r]);
      *reinterpret_cast<u16x4*>(&p_lds[w][l15][kb * 16 + g * 4]) = pk;
    }
    const short8 bp0 = ld8(&p_lds[w][l15][g * 8]);
    const short8 bp1 = ld8(&p_lds[w][l15][32 + g * 8]);
    // ---- O^T += V^T P
    o0 = __builtin_amdgcn_mfma_f32_16x16x32_bf16(av00, bp0, o0, 0, 0, 0);
    o0 = __builtin_amdgcn_mfma_f32_16x16x32_bf16(av01, bp1, o0, 0, 0, 0);
    o1 = __builtin_amdgcn_mfma_f32_16x16x32_bf16(av10, bp0, o1, 0, 0, 0);
    o1 = __builtin_amdgcn_mfma_f32_16x16x32_bf16(av11, bp1, o1, 0, 0, 0);
#pragma unroll
    for (int kb = 0; kb < 4; ++kb) bc[kb] = bn[kb];
  }
  // publish per-chunk partials: o_lds[w][q][d]
#pragma unroll
  for (int r = 0; r < 4; ++r) {
    o_lds[w][l15][g * 4 + r] = o0[r];
    o_lds[w][l15][16 + g * 4 + r] = o1[r];
  }
  if (l < 16) {
    ml_lds[w][0][l15] = m;
    ml_lds[w][1][l15] = lsum;
  }
  __syncthreads();
  // combine 4 chunks, apply gate, emit bf16 [q][h*32+ch]
#pragma unroll
  for (int it = 0; it < 2; ++it) {
    const int e = tid + it * 256;
    const int ql = e >> 5, ch = e & 31;
    const float m01 = fmaxf(ml_lds[0][0][ql], ml_lds[1][0][ql]);
    const float m23 = fmaxf(ml_lds[2][0][ql], ml_lds[3][0][ql]);
    const float mm = fmaxf(m01, m23);
    float L = 0.f, acc = 0.f;
#pragma unroll
    for (int cidx = 0; cidx < 4; ++cidx) {
      const float scc = __expf(ml_lds[cidx][0][ql] - mm);
      L += ml_lds[cidx][1][ql] * scc;
      acc += o_lds[cidx][ql][ch] * scc;
    }
    const size_t idx = (size_t)(qb + ql) * HC + h * CH + ch;
    og[idx] = f2bf((acc / L) * gate[idx]);
  }
}

// ---------------- K3: output projection + bias ----------------
__global__ __launch_bounds__(256) void k3_oproj(
    const unsigned short* __restrict__ og, const unsigned short* __restrict__ wToT,
    const float* __restrict__ bo, float* __restrict__ out) {
  const int tid = threadIdx.x;
  const int w = tid >> 6, l = tid & 63, l15 = l & 15, g = l >> 4;
  const int row0 = blockIdx.x * 64 + (w >> 1) * 32;
  const int col0 = blockIdx.y * 64 + (w & 1) * 32;
  f32x4 acc[2][2] = {};
  for (int kk = 0; kk < HC; kk += 32) {
    short8 a[2], b[2];
#pragma unroll
    for (int fi = 0; fi < 2; ++fi)
      a[fi] = ld8(og + (size_t)(row0 + fi * 16 + l15) * HC + kk + g * 8);
#pragma unroll
    for (int fj = 0; fj < 2; ++fj)
      b[fj] = ld8(wToT + (size_t)(col0 + fj * 16 + l15) * HC + kk + g * 8);
#pragma unroll
    for (int fi = 0; fi < 2; ++fi)
#pragma unroll
      for (int fj = 0; fj < 2; ++fj)
        acc[fi][fj] = __builtin_amdgcn_mfma_f32_16x16x32_bf16(a[fi], b[fj], acc[fi][fj], 0, 0, 0);
  }
#pragma unroll
  for (int fi = 0; fi < 2; ++fi)
#pragma unroll
    for (int fj = 0; fj < 2; ++fj)
#pragma unroll
      for (int r = 0; r < 4; ++r) {
        const int row = row0 + fi * 16 + g * 4 + r;
        const int col = col0 + fj * 16 + l15;
        out[(size_t)row * CIN + col] = acc[fi][fj][r] + bo[col];
      }
}

extern "C" void kernel_launch(void* const* d_in, const int* in_sizes, int n_in,
                              void* d_out, int out_size, void* d_ws, size_t ws_size,
                              hipStream_t stream) {
  const float* qx = (const float*)d_in[0];
  const float* kvx = (const float*)d_in[1];
  const float* pb = (const float*)d_in[2];
  const float* mbias = (const float*)d_in[3];
  const float* wq = (const float*)d_in[4];
  const float* wk = (const float*)d_in[5];
  const float* wv = (const float*)d_in[6];
  const float* wg = (const float*)d_in[7];
  const float* bg = (const float*)d_in[8];
  const float* wo = (const float*)d_in[9];
  const float* bo = (const float*)d_in[10];
  char* ws = (char*)d_ws;
  // workspace layout (bytes): wT 655360 | qh 1M | kh2 1M | va 1M | og 1M | gate 2M
  unsigned short* wT = (unsigned short*)(ws);
  unsigned short* qh = (unsigned short*)(ws + 655360);
  unsigned short* kh2 = (unsigned short*)(ws + 655360 + (1u << 20));
  unsigned short* va = (unsigned short*)(ws + 655360 + 2u * (1u << 20));
  unsigned short* og = (unsigned short*)(ws + 655360 + 3u * (1u << 20));
  float* gate = (float*)(ws + 655360 + 4u * (1u << 20));
  float* out = (float*)d_out;

  k0_wtrans<<<dim3(8, 8, 5), 256, 0, stream>>>(wq, wk, wv, wg, wo, wT);
  k1_proj<<<dim3(32, 4, 4), 256, 0, stream>>>(qx, kvx, wT, bg, qh, kh2, va, gate);
  k2_attn<<<dim3(128, 8), 256, 0, stream>>>(qh, kh2, va, pb, mbias, gate, og);
  k3_oproj<<<dim3(32, 4), 256, 0, stream>>>(og, wT + 4 * 256 * 256, bo, out);
}